// Round 13
// baseline (1212.320 us; speedup 1.0000x reference)
//
#include <hip/hip_runtime.h>

#define N1 1000000
#define N2 400000
#define N4 150000
#define N8 60000
#define N16 20000

constexpr float BN_EPS = 1e-5f;

__device__ __forceinline__ float lrelu(float x) { return fmaxf(x, 0.1f * x); }

// Fold all BatchNorm params into scale/shift once per call.
// fold: enc0 sc[32],sh[32] @0; encR b: sc[32],sh[32] @64+b*64; dec i: sc[64],sh[64] @320+i*128.
__global__ void k_fold(const float* g0, const float* be0, const float* m0, const float* v0,
                       const float* gR, const float* beR, const float* mR, const float* vR,
                       const float* gD, const float* beD, const float* mD, const float* vD,
                       float* fold) {
  int t = threadIdx.x;
  if (t < 32) {
    float sc = g0[t] * rsqrtf(v0[t] + BN_EPS);
    fold[t] = sc;
    fold[32 + t] = be0[t] - m0[t] * sc;
  }
  if (t < 128) {
    int b = t >> 5, c = t & 31;
    float sc = gR[b * 32 + c] * rsqrtf(vR[b * 32 + c] + BN_EPS);
    fold[64 + b * 64 + c] = sc;
    fold[64 + b * 64 + 32 + c] = beR[b * 32 + c] - mR[b * 32 + c] * sc;
  }
  for (int i = t; i < 320; i += blockDim.x) {
    int b = i >> 6, c = i & 63;
    float sc = gD[b * 64 + c] * rsqrtf(vD[b * 64 + c] + BN_EPS);
    fold[320 + b * 128 + c] = sc;
    fold[320 + b * 128 + 64 + c] = beD[b * 64 + c] - mD[b * 64 + c] * sc;
  }
}

// Build per-segment linked lists. head pre-set to -1. One 4B atomic per row.
__global__ __launch_bounds__(256) void k_fill(const int* __restrict__ idx,
                                              int* head, int* nxt, int n) {
  int i = blockIdx.x * 256 + threadIdx.x;
  if (i < n) nxt[i] = atomicExch(&head[idx[i]], i);
}

// Segment max by chained gather: one wave per segment, one thread per channel.
__global__ __launch_bounds__(256) void k_gmax(
    const float* __restrict__ src, const int* __restrict__ head,
    const int* __restrict__ nxt, float* __restrict__ dst, int nseg) {
  int t = blockIdx.x * 256 + threadIdx.x;
  int seg = t >> 6, ch = t & 63;
  if (seg >= nseg) return;
  float m = -INFINITY;
  for (int p = head[seg]; p >= 0; p = nxt[p])
    m = fmaxf(m, src[(size_t)p * 64 + ch]);
  dst[(size_t)seg * 64 + ch] = (m == -INFINITY) ? 0.0f : m;
}

// ---------------- scalar-weight GEMM kernels ----------------
// lane = output row, wave w = col slice. Weights wave-uniform -> s_load.
// LDS rows stride 68 floats (16B-aligned, conflict-free b128); hS stride 36.
// dec2/lastT: 2 rows/thread (128-row tile) -> halves weight s_loads per FMA.

// encoder block 0: x[9] -> h[32] (lrelu,BN) -> out[64] (lrelu)
__global__ __launch_bounds__(256) void k_enc0_s(
    const float* __restrict__ x,
    const float* __restrict__ W1, const float* __restrict__ b1,
    const float* __restrict__ fold,
    const float* __restrict__ W2, const float* __restrict__ b2,
    float* __restrict__ out, int n) {
  __shared__ float xS[64 * 9];
  __shared__ float hS[64 * 36];
  int t = threadIdx.x;
  int lane = t & 63;
  int w = __builtin_amdgcn_readfirstlane(t >> 6);
  int R = blockIdx.x * 64;

  {
    size_t lim = (size_t)n * 9 - 1;
    for (int i = t; i < 576; i += 256) {
      size_t gi = (size_t)R * 9 + i;
      if (gi > lim) gi = lim;
      xS[i] = x[gi];
    }
  }
  __syncthreads();

  // phase 1: h cols 8w..8w+7, K=9
  {
    const float* W1p = W1 + w * 8;
    float xr[9];
#pragma unroll
    for (int k = 0; k < 9; ++k) xr[k] = xS[lane * 9 + k];
    float acc[8];
#pragma unroll
    for (int c = 0; c < 8; ++c) acc[c] = b1[w * 8 + c];
#pragma unroll
    for (int k = 0; k < 9; ++k) {
#pragma unroll
      for (int c = 0; c < 8; ++c) acc[c] = fmaf(xr[k], W1p[k * 32 + c], acc[c]);
    }
    float4 o0, o1;
    o0.x = lrelu(acc[0]) * fold[w * 8 + 0] + fold[32 + w * 8 + 0];
    o0.y = lrelu(acc[1]) * fold[w * 8 + 1] + fold[32 + w * 8 + 1];
    o0.z = lrelu(acc[2]) * fold[w * 8 + 2] + fold[32 + w * 8 + 2];
    o0.w = lrelu(acc[3]) * fold[w * 8 + 3] + fold[32 + w * 8 + 3];
    o1.x = lrelu(acc[4]) * fold[w * 8 + 4] + fold[32 + w * 8 + 4];
    o1.y = lrelu(acc[5]) * fold[w * 8 + 5] + fold[32 + w * 8 + 5];
    o1.z = lrelu(acc[6]) * fold[w * 8 + 6] + fold[32 + w * 8 + 6];
    o1.w = lrelu(acc[7]) * fold[w * 8 + 7] + fold[32 + w * 8 + 7];
    *(float4*)(hS + lane * 36 + w * 8) = o0;
    *(float4*)(hS + lane * 36 + w * 8 + 4) = o1;
  }
  __syncthreads();

  // phase 2: out cols 16w..16w+15, K=32, b128 chunks of 8
  {
    const float* W2p = W2 + w * 16;
    float o[16];
#pragma unroll
    for (int c = 0; c < 16; ++c) o[c] = b2[w * 16 + c];
    for (int k0 = 0; k0 < 32; k0 += 8) {
      float4 av0 = *(const float4*)(hS + lane * 36 + k0);
      float4 av1 = *(const float4*)(hS + lane * 36 + k0 + 4);
      float a[8] = {av0.x, av0.y, av0.z, av0.w, av1.x, av1.y, av1.z, av1.w};
#pragma unroll
      for (int j = 0; j < 8; ++j) {
#pragma unroll
        for (int c = 0; c < 16; ++c)
          o[c] = fmaf(a[j], W2p[(k0 + j) * 64 + c], o[c]);
      }
    }
    int gr = R + lane;
    if (gr < n) {
      float* op = out + (size_t)gr * 64 + w * 16;
#pragma unroll
      for (int c = 0; c < 16; ++c) op[c] = lrelu(o[c]);
    }
  }
}

// encoder blocks 1..4: in[64] -> h[32] (lrelu,BN) -> out[64] (lrelu)
__global__ __launch_bounds__(256) void k_encR_s(
    const float* __restrict__ xin,
    const float* __restrict__ W1, const float* __restrict__ b1,
    const float* __restrict__ fold,
    const float* __restrict__ W2, const float* __restrict__ b2,
    float* __restrict__ out, int n) {
  __shared__ float inS[64 * 68];
  __shared__ float hS[64 * 36];
  int t = threadIdx.x;
  int lane = t & 63;
  int w = __builtin_amdgcn_readfirstlane(t >> 6);
  int R = blockIdx.x * 64;

  for (int f = t; f < 1024; f += 256) {
    int row = f >> 4, c4 = (f & 15) << 2;
    int gr = R + row; if (gr >= n) gr = n - 1;
    *(float4*)(inS + row * 68 + c4) = *(const float4*)(xin + (size_t)gr * 64 + c4);
  }
  __syncthreads();

  // phase 1: h cols 8w..8w+7, K=64, b128 chunks of 8
  {
    const float* W1p = W1 + w * 8;
    float acc[8];
#pragma unroll
    for (int c = 0; c < 8; ++c) acc[c] = b1[w * 8 + c];
    for (int k0 = 0; k0 < 64; k0 += 8) {
      float4 av0 = *(const float4*)(inS + lane * 68 + k0);
      float4 av1 = *(const float4*)(inS + lane * 68 + k0 + 4);
      float a[8] = {av0.x, av0.y, av0.z, av0.w, av1.x, av1.y, av1.z, av1.w};
#pragma unroll
      for (int j = 0; j < 8; ++j) {
#pragma unroll
        for (int c = 0; c < 8; ++c)
          acc[c] = fmaf(a[j], W1p[(k0 + j) * 32 + c], acc[c]);
      }
    }
    float4 o0, o1;
    o0.x = lrelu(acc[0]) * fold[w * 8 + 0] + fold[32 + w * 8 + 0];
    o0.y = lrelu(acc[1]) * fold[w * 8 + 1] + fold[32 + w * 8 + 1];
    o0.z = lrelu(acc[2]) * fold[w * 8 + 2] + fold[32 + w * 8 + 2];
    o0.w = lrelu(acc[3]) * fold[w * 8 + 3] + fold[32 + w * 8 + 3];
    o1.x = lrelu(acc[4]) * fold[w * 8 + 4] + fold[32 + w * 8 + 4];
    o1.y = lrelu(acc[5]) * fold[w * 8 + 5] + fold[32 + w * 8 + 5];
    o1.z = lrelu(acc[6]) * fold[w * 8 + 6] + fold[32 + w * 8 + 6];
    o1.w = lrelu(acc[7]) * fold[w * 8 + 7] + fold[32 + w * 8 + 7];
    *(float4*)(hS + lane * 36 + w * 8) = o0;
    *(float4*)(hS + lane * 36 + w * 8 + 4) = o1;
  }
  __syncthreads();

  // phase 2: out cols 16w..16w+15, K=32, b128 chunks of 8
  {
    const float* W2p = W2 + w * 16;
    float o[16];
#pragma unroll
    for (int c = 0; c < 16; ++c) o[c] = b2[w * 16 + c];
    for (int k0 = 0; k0 < 32; k0 += 8) {
      float4 av0 = *(const float4*)(hS + lane * 36 + k0);
      float4 av1 = *(const float4*)(hS + lane * 36 + k0 + 4);
      float a[8] = {av0.x, av0.y, av0.z, av0.w, av1.x, av1.y, av1.z, av1.w};
#pragma unroll
      for (int j = 0; j < 8; ++j) {
#pragma unroll
        for (int c = 0; c < 16; ++c)
          o[c] = fmaf(a[j], W2p[(k0 + j) * 64 + c], o[c]);
      }
    }
    int gr = R + lane;
    if (gr < n) {
      float* op = out + (size_t)gr * 64 + w * 16;
#pragma unroll
      for (int c = 0; c < 16; ++c) op[c] = lrelu(o[c]);
    }
  }
}

// lastT = src @ decW[64:128] + decb, 2 rows/thread (128-row tile)
__global__ __launch_bounds__(256) void k_lastT(
    const float* __restrict__ src, const float* __restrict__ decW,
    const float* __restrict__ decb, float* __restrict__ lT, int n) {
  __shared__ float sS[128 * 68];
  int t = threadIdx.x;
  int lane = t & 63;
  int w = __builtin_amdgcn_readfirstlane(t >> 6);
  int R = blockIdx.x * 128;

  for (int f = t; f < 2048; f += 256) {
    int row = f >> 4, c4 = (f & 15) << 2;
    int gr = R + row; if (gr >= n) gr = n - 1;
    *(float4*)(sS + row * 68 + c4) = *(const float4*)(src + (size_t)gr * 64 + c4);
  }
  __syncthreads();

  const float* Dp = decW + 64 * 64 + w * 16;  // bottom half rows
  float o0[16], o1[16];
#pragma unroll
  for (int c = 0; c < 16; ++c) { o0[c] = decb[w * 16 + c]; o1[c] = o0[c]; }
  for (int k0 = 0; k0 < 64; k0 += 8) {
    float4 av0 = *(const float4*)(sS + lane * 68 + k0);
    float4 av1 = *(const float4*)(sS + lane * 68 + k0 + 4);
    float4 bv0 = *(const float4*)(sS + (lane + 64) * 68 + k0);
    float4 bv1 = *(const float4*)(sS + (lane + 64) * 68 + k0 + 4);
    float a[8] = {av0.x, av0.y, av0.z, av0.w, av1.x, av1.y, av1.z, av1.w};
    float b[8] = {bv0.x, bv0.y, bv0.z, bv0.w, bv1.x, bv1.y, bv1.z, bv1.w};
#pragma unroll
    for (int j = 0; j < 8; ++j) {
#pragma unroll
      for (int c = 0; c < 16; ++c) {
        float wv = Dp[(k0 + j) * 64 + c];
        o0[c] = fmaf(a[j], wv, o0[c]);
        o1[c] = fmaf(b[j], wv, o1[c]);
      }
    }
  }
  int g0 = R + lane, g1 = R + 64 + lane;
  if (g0 < n) {
    float* op = lT + (size_t)g0 * 64 + w * 16;
#pragma unroll
    for (int c = 0; c < 16; ++c) op[c] = o0[c];
  }
  if (g1 < n) {
    float* op = lT + (size_t)g1 * 64 + w * 16;
#pragma unroll
    for (int c = 0; c < 16; ++c) op[c] = o1[c];
  }
}

// decoder: out = lrelu(BN(lrelu(cur@mlpW+mlpb) @ decW[0:64] + lastT[lrow]))
// In place on `inout`. 2 rows/thread (128-row tile, 34.8 KB LDS).
__global__ __launch_bounds__(256) void k_dec2(
    float* inout, const float* __restrict__ lT, const int* __restrict__ idx,
    const float* __restrict__ mlpW, const float* __restrict__ mlpb,
    const float* __restrict__ decW, const float* __restrict__ fold, int n) {
  __shared__ float curS[128 * 68];
  int t = threadIdx.x;
  int lane = t & 63;
  int w = __builtin_amdgcn_readfirstlane(t >> 6);
  int R = blockIdx.x * 128;

  for (int f = t; f < 2048; f += 256) {
    int row = f >> 4, c4 = (f & 15) << 2;
    int gr = R + row; if (gr >= n) gr = n - 1;
    *(float4*)(curS + row * 68 + c4) = *(const float4*)(inout + (size_t)gr * 64 + c4);
  }

  // issue lastT gathers early (consumed after phase 1)
  int g0r = R + lane; if (g0r >= n) g0r = n - 1;
  int g1r = R + 64 + lane; if (g1r >= n) g1r = n - 1;
  int g0i = idx ? idx[g0r] : g0r;
  int g1i = idx ? idx[g1r] : g1r;
  const float* lpa = lT + (size_t)g0i * 64 + w * 16;
  const float* lpb = lT + (size_t)g1i * 64 + w * 16;
  float4 la0 = *(const float4*)(lpa + 0);
  float4 la1 = *(const float4*)(lpa + 4);
  float4 la2 = *(const float4*)(lpa + 8);
  float4 la3 = *(const float4*)(lpa + 12);
  float4 lb0 = *(const float4*)(lpb + 0);
  float4 lb1 = *(const float4*)(lpb + 4);
  float4 lb2 = *(const float4*)(lpb + 8);
  float4 lb3 = *(const float4*)(lpb + 12);

  __syncthreads();

  // phase 1: skip cols 16w..16w+15 for rows lane, lane+64; K=64
  float s0[16], s1[16];
  {
    const float* Mp = mlpW + w * 16;
#pragma unroll
    for (int c = 0; c < 16; ++c) { s0[c] = mlpb[w * 16 + c]; s1[c] = s0[c]; }
    for (int k0 = 0; k0 < 64; k0 += 8) {
      float4 av0 = *(const float4*)(curS + lane * 68 + k0);
      float4 av1 = *(const float4*)(curS + lane * 68 + k0 + 4);
      float4 bv0 = *(const float4*)(curS + (lane + 64) * 68 + k0);
      float4 bv1 = *(const float4*)(curS + (lane + 64) * 68 + k0 + 4);
      float a[8] = {av0.x, av0.y, av0.z, av0.w, av1.x, av1.y, av1.z, av1.w};
      float b[8] = {bv0.x, bv0.y, bv0.z, bv0.w, bv1.x, bv1.y, bv1.z, bv1.w};
#pragma unroll
      for (int j = 0; j < 8; ++j) {
#pragma unroll
        for (int c = 0; c < 16; ++c) {
          float wv = Mp[(k0 + j) * 64 + c];
          s0[c] = fmaf(a[j], wv, s0[c]);
          s1[c] = fmaf(b[j], wv, s1[c]);
        }
      }
    }
  }
  __syncthreads();  // all reads of curS done
  {
    float4 t0 = {lrelu(s0[0]), lrelu(s0[1]), lrelu(s0[2]), lrelu(s0[3])};
    float4 t1 = {lrelu(s0[4]), lrelu(s0[5]), lrelu(s0[6]), lrelu(s0[7])};
    float4 t2 = {lrelu(s0[8]), lrelu(s0[9]), lrelu(s0[10]), lrelu(s0[11])};
    float4 t3 = {lrelu(s0[12]), lrelu(s0[13]), lrelu(s0[14]), lrelu(s0[15])};
    *(float4*)(curS + lane * 68 + w * 16 + 0) = t0;
    *(float4*)(curS + lane * 68 + w * 16 + 4) = t1;
    *(float4*)(curS + lane * 68 + w * 16 + 8) = t2;
    *(float4*)(curS + lane * 68 + w * 16 + 12) = t3;
    float4 u0 = {lrelu(s1[0]), lrelu(s1[1]), lrelu(s1[2]), lrelu(s1[3])};
    float4 u1 = {lrelu(s1[4]), lrelu(s1[5]), lrelu(s1[6]), lrelu(s1[7])};
    float4 u2 = {lrelu(s1[8]), lrelu(s1[9]), lrelu(s1[10]), lrelu(s1[11])};
    float4 u3 = {lrelu(s1[12]), lrelu(s1[13]), lrelu(s1[14]), lrelu(s1[15])};
    *(float4*)(curS + (lane + 64) * 68 + w * 16 + 0) = u0;
    *(float4*)(curS + (lane + 64) * 68 + w * 16 + 4) = u1;
    *(float4*)(curS + (lane + 64) * 68 + w * 16 + 8) = u2;
    *(float4*)(curS + (lane + 64) * 68 + w * 16 + 12) = u3;
  }
  __syncthreads();

  // phase 2: out = skip @ decW_top + lastT, K=64, both rows
  {
    float o0[16], o1[16];
    o0[0] = la0.x; o0[1] = la0.y; o0[2] = la0.z; o0[3] = la0.w;
    o0[4] = la1.x; o0[5] = la1.y; o0[6] = la1.z; o0[7] = la1.w;
    o0[8] = la2.x; o0[9] = la2.y; o0[10] = la2.z; o0[11] = la2.w;
    o0[12] = la3.x; o0[13] = la3.y; o0[14] = la3.z; o0[15] = la3.w;
    o1[0] = lb0.x; o1[1] = lb0.y; o1[2] = lb0.z; o1[3] = lb0.w;
    o1[4] = lb1.x; o1[5] = lb1.y; o1[6] = lb1.z; o1[7] = lb1.w;
    o1[8] = lb2.x; o1[9] = lb2.y; o1[10] = lb2.z; o1[11] = lb2.w;
    o1[12] = lb3.x; o1[13] = lb3.y; o1[14] = lb3.z; o1[15] = lb3.w;

    const float* Dp = decW + w * 16;  // top half rows
    for (int k0 = 0; k0 < 64; k0 += 8) {
      float4 av0 = *(const float4*)(curS + lane * 68 + k0);
      float4 av1 = *(const float4*)(curS + lane * 68 + k0 + 4);
      float4 bv0 = *(const float4*)(curS + (lane + 64) * 68 + k0);
      float4 bv1 = *(const float4*)(curS + (lane + 64) * 68 + k0 + 4);
      float a[8] = {av0.x, av0.y, av0.z, av0.w, av1.x, av1.y, av1.z, av1.w};
      float b[8] = {bv0.x, bv0.y, bv0.z, bv0.w, bv1.x, bv1.y, bv1.z, bv1.w};
#pragma unroll
      for (int j = 0; j < 8; ++j) {
#pragma unroll
        for (int c = 0; c < 16; ++c) {
          float wv = Dp[(k0 + j) * 64 + c];
          o0[c] = fmaf(a[j], wv, o0[c]);
          o1[c] = fmaf(b[j], wv, o1[c]);
        }
      }
    }
    int g0 = R + lane, g1 = R + 64 + lane;
    if (g0 < n) {
      float* op = inout + (size_t)g0 * 64 + w * 16;
#pragma unroll
      for (int c = 0; c < 16; ++c) {
        float sc = fold[w * 16 + c], sh = fold[64 + w * 16 + c];
        op[c] = lrelu(o0[c] * sc + sh);
      }
    }
    if (g1 < n) {
      float* op = inout + (size_t)g1 * 64 + w * 16;
#pragma unroll
      for (int c = 0; c < 16; ++c) {
        float sc = fold[w * 16 + c], sh = fold[64 + w * 16 + c];
        op[c] = lrelu(o1[c] * sc + sh);
      }
    }
  }
}

extern "C" void kernel_launch(void* const* d_in, const int* in_sizes, int n_in,
                              void* d_out, int out_size, void* d_ws, size_t ws_size,
                              hipStream_t stream) {
  const float* pt   = (const float*)d_in[0];
  const int* inv2   = (const int*)d_in[1];
  const int* inv4   = (const int*)d_in[2];
  const int* inv8   = (const int*)d_in[3];
  const int* inv16  = (const int*)d_in[4];
  const float* e0W1 = (const float*)d_in[5];
  const float* e0b1 = (const float*)d_in[6];
  const float* e0g  = (const float*)d_in[7];
  const float* e0be = (const float*)d_in[8];
  const float* e0m  = (const float*)d_in[9];
  const float* e0v  = (const float*)d_in[10];
  const float* e0W2 = (const float*)d_in[11];
  const float* e0b2 = (const float*)d_in[12];
  const float* eRW1 = (const float*)d_in[13];
  const float* eRb1 = (const float*)d_in[14];
  const float* eRg  = (const float*)d_in[15];
  const float* eRbe = (const float*)d_in[16];
  const float* eRm  = (const float*)d_in[17];
  const float* eRv  = (const float*)d_in[18];
  const float* eRW2 = (const float*)d_in[19];
  const float* eRb2 = (const float*)d_in[20];
  const float* mlpW = (const float*)d_in[21];
  const float* mlpb = (const float*)d_in[22];
  const float* decW = (const float*)d_in[23];
  const float* decb = (const float*)d_in[24];
  const float* decg = (const float*)d_in[25];
  const float* decbe= (const float*)d_in[26];
  const float* decm = (const float*)d_in[27];
  const float* decv = (const float*)d_in[28];

  float* s1 = (float*)d_out;
  float* s2 = s1 + (size_t)N1 * 64;
  float* s3 = s2 + (size_t)N2 * 64;
  float* s4 = s3 + (size_t)N4 * 64;
  float* s5 = s4 + (size_t)N8 * 64;

  // workspace: fold | oA (N2*64 f, reused as lastT) | oB (N4*64 f) | head | nxt
  float* fold = (float*)d_ws;
  float* oA   = fold + 1024;
  float* oB   = oA + (size_t)N2 * 64;
  int* head   = (int*)(oB + (size_t)N4 * 64);
  int* nxt    = head + N2;
  float* lT   = oA;  // free after encoders

  k_fold<<<1, 320, 0, stream>>>(e0g, e0be, e0m, e0v, eRg, eRbe, eRm, eRv,
                                decg, decbe, decm, decv, fold);

  // ---- level 1: enc0 on N1, pool -> oA [N2] ----
  hipMemsetAsync(head, 0xFF, (size_t)N2 * 4, stream);
  k_fill<<<(N1 + 255) / 256, 256, 0, stream>>>(inv2, head, nxt, N1);
  k_enc0_s<<<(N1 + 63) / 64, 256, 0, stream>>>(pt, e0W1, e0b1, fold, e0W2, e0b2, s1, N1);
  k_gmax<<<((size_t)N2 * 64 + 255) / 256, 256, 0, stream>>>(s1, head, nxt, oA, N2);

  // ---- level 2: encR[0] on N2, pool -> oB [N4] ----
  hipMemsetAsync(head, 0xFF, (size_t)N4 * 4, stream);
  k_fill<<<(N2 + 255) / 256, 256, 0, stream>>>(inv4, head, nxt, N2);
  k_encR_s<<<(N2 + 63) / 64, 256, 0, stream>>>(oA, eRW1 + 0 * 2048, eRb1 + 0 * 32,
                                               fold + 64 + 0 * 64, eRW2 + 0 * 2048,
                                               eRb2 + 0 * 64, s2, N2);
  k_gmax<<<((size_t)N4 * 64 + 255) / 256, 256, 0, stream>>>(s2, head, nxt, oB, N4);

  // ---- level 3: encR[1] on N4, pool -> oA [N8] ----
  hipMemsetAsync(head, 0xFF, (size_t)N8 * 4, stream);
  k_fill<<<(N4 + 255) / 256, 256, 0, stream>>>(inv8, head, nxt, N4);
  k_encR_s<<<(N4 + 63) / 64, 256, 0, stream>>>(oB, eRW1 + 1 * 2048, eRb1 + 1 * 32,
                                               fold + 64 + 1 * 64, eRW2 + 1 * 2048,
                                               eRb2 + 1 * 64, s3, N4);
  k_gmax<<<((size_t)N8 * 64 + 255) / 256, 256, 0, stream>>>(s3, head, nxt, oA, N8);

  // ---- level 4: encR[2] on N8, pool -> oB [N16] ----
  hipMemsetAsync(head, 0xFF, (size_t)N16 * 4, stream);
  k_fill<<<(N8 + 255) / 256, 256, 0, stream>>>(inv16, head, nxt, N8);
  k_encR_s<<<(N8 + 63) / 64, 256, 0, stream>>>(oA, eRW1 + 2 * 2048, eRb1 + 2 * 32,
                                               fold + 64 + 2 * 64, eRW2 + 2 * 2048,
                                               eRb2 + 2 * 64, s4, N8);
  k_gmax<<<((size_t)N16 * 64 + 255) / 256, 256, 0, stream>>>(s4, head, nxt, oB, N16);

  // ---- level 5: encR[3] on N16 ----
  k_encR_s<<<(N16 + 63) / 64, 256, 0, stream>>>(oB, eRW1 + 3 * 2048, eRb1 + 3 * 32,
                                                fold + 64 + 3 * 64, eRW2 + 3 * 2048,
                                                eRb2 + 3 * 64, s5, N16);

  // ---- decoders: lastT = prev_out @ decW_bot + decb, then fused dec ----
  k_lastT<<<(N16 + 127) / 128, 256, 0, stream>>>(s5, decW + 0 * 8192, decb + 0 * 64, lT, N16);
  k_dec2<<<(N16 + 127) / 128, 256, 0, stream>>>(s5, lT, nullptr, mlpW + 0 * 4096, mlpb + 0 * 64,
                                                decW + 0 * 8192, fold + 320 + 0 * 128, N16);
  k_lastT<<<(N16 + 127) / 128, 256, 0, stream>>>(s5, decW + 1 * 8192, decb + 1 * 64, lT, N16);
  k_dec2<<<(N8 + 127) / 128, 256, 0, stream>>>(s4, lT, inv16, mlpW + 1 * 4096, mlpb + 1 * 64,
                                               decW + 1 * 8192, fold + 320 + 1 * 128, N8);
  k_lastT<<<(N8 + 127) / 128, 256, 0, stream>>>(s4, decW + 2 * 8192, decb + 2 * 64, lT, N8);
  k_dec2<<<(N4 + 127) / 128, 256, 0, stream>>>(s3, lT, inv8, mlpW + 2 * 4096, mlpb + 2 * 64,
                                               decW + 2 * 8192, fold + 320 + 2 * 128, N4);
  k_lastT<<<(N4 + 127) / 128, 256, 0, stream>>>(s3, decW + 3 * 8192, decb + 3 * 64, lT, N4);
  k_dec2<<<(N2 + 127) / 128, 256, 0, stream>>>(s2, lT, inv4, mlpW + 3 * 4096, mlpb + 3 * 64,
                                               decW + 3 * 8192, fold + 320 + 3 * 128, N2);
  k_lastT<<<(N2 + 127) / 128, 256, 0, stream>>>(s2, decW + 4 * 8192, decb + 4 * 64, lT, N2);
  k_dec2<<<(N1 + 127) / 128, 256, 0, stream>>>(s1, lT, inv2, mlpW + 4 * 4096, mlpb + 4 * 64,
                                               decW + 4 * 8192, fold + 320 + 4 * 128, N1);
}

// Round 14
// 1135.462 us; speedup vs baseline: 1.0677x; 1.0677x over previous
//
#include <hip/hip_runtime.h>

#define N1 1000000
#define N2 400000
#define N4 150000
#define N8 60000
#define N16 20000

constexpr float BN_EPS = 1e-5f;

__device__ __forceinline__ float lrelu(float x) { return fmaxf(x, 0.1f * x); }

// Fold all BatchNorm params into scale/shift once per call.
__global__ void k_fold(const float* g0, const float* be0, const float* m0, const float* v0,
                       const float* gR, const float* beR, const float* mR, const float* vR,
                       const float* gD, const float* beD, const float* mD, const float* vD,
                       float* fold) {
  int t = threadIdx.x;
  if (t < 32) {
    float sc = g0[t] * rsqrtf(v0[t] + BN_EPS);
    fold[t] = sc;
    fold[32 + t] = be0[t] - m0[t] * sc;
  }
  if (t < 128) {
    int b = t >> 5, c = t & 31;
    float sc = gR[b * 32 + c] * rsqrtf(vR[b * 32 + c] + BN_EPS);
    fold[64 + b * 64 + c] = sc;
    fold[64 + b * 64 + 32 + c] = beR[b * 32 + c] - mR[b * 32 + c] * sc;
  }
  for (int i = t; i < 320; i += blockDim.x) {
    int b = i >> 6, c = i & 63;
    float sc = gD[b * 64 + c] * rsqrtf(vD[b * 64 + c] + BN_EPS);
    fold[320 + b * 128 + c] = sc;
    fold[320 + b * 128 + 64 + c] = beD[b * 64 + c] - mD[b * 64 + c] * sc;
  }
}

// Build per-segment linked lists. head pre-set to -1. One 4B atomic per row.
__global__ __launch_bounds__(256) void k_fill(const int* __restrict__ idx,
                                              int* head, int* nxt, int n) {
  int i = blockIdx.x * 256 + threadIdx.x;
  if (i < n) nxt[i] = atomicExch(&head[idx[i]], i);
}

// Segment max by chained gather: one wave per segment, one thread per channel.
__global__ __launch_bounds__(256) void k_gmax(
    const float* __restrict__ src, const int* __restrict__ head,
    const int* __restrict__ nxt, float* __restrict__ dst, int nseg) {
  int t = blockIdx.x * 256 + threadIdx.x;
  int seg = t >> 6, ch = t & 63;
  if (seg >= nseg) return;
  float m = -INFINITY;
  for (int p = head[seg]; p >= 0; p = nxt[p])
    m = fmaxf(m, src[(size_t)p * 64 + ch]);
  dst[(size_t)seg * 64 + ch] = (m == -INFINITY) ? 0.0f : m;
}

// ---------------- scalar-weight GEMM kernels ----------------
// Weights wave-uniform -> s_load. LDS rows stride 68/36 floats (16B-aligned,
// conflict-free b128). Encoders: 64-row tile, 256 thr, 16-col waves (R12 best).
// dec2/lastT: 128-row tile, 512 thr (8 waves), 8-col x 2-row per thread:
// 2-row halves weight s_loads/FMA, 512-thr block keeps 100% occupancy
// (34.8 KB x 4 blocks/CU = 2048 thr), <=64 VGPR target.

// encoder block 0: x[9] -> h[32] (lrelu,BN) -> out[64] (lrelu)
__global__ __launch_bounds__(256) void k_enc0_s(
    const float* __restrict__ x,
    const float* __restrict__ W1, const float* __restrict__ b1,
    const float* __restrict__ fold,
    const float* __restrict__ W2, const float* __restrict__ b2,
    float* __restrict__ out, int n) {
  __shared__ float xS[64 * 9];
  __shared__ float hS[64 * 36];
  int t = threadIdx.x;
  int lane = t & 63;
  int w = __builtin_amdgcn_readfirstlane(t >> 6);
  int R = blockIdx.x * 64;

  {
    size_t lim = (size_t)n * 9 - 1;
    for (int i = t; i < 576; i += 256) {
      size_t gi = (size_t)R * 9 + i;
      if (gi > lim) gi = lim;
      xS[i] = x[gi];
    }
  }
  __syncthreads();

  {
    const float* W1p = W1 + w * 8;
    float xr[9];
#pragma unroll
    for (int k = 0; k < 9; ++k) xr[k] = xS[lane * 9 + k];
    float acc[8];
#pragma unroll
    for (int c = 0; c < 8; ++c) acc[c] = b1[w * 8 + c];
#pragma unroll
    for (int k = 0; k < 9; ++k) {
#pragma unroll
      for (int c = 0; c < 8; ++c) acc[c] = fmaf(xr[k], W1p[k * 32 + c], acc[c]);
    }
    float4 o0, o1;
    o0.x = lrelu(acc[0]) * fold[w * 8 + 0] + fold[32 + w * 8 + 0];
    o0.y = lrelu(acc[1]) * fold[w * 8 + 1] + fold[32 + w * 8 + 1];
    o0.z = lrelu(acc[2]) * fold[w * 8 + 2] + fold[32 + w * 8 + 2];
    o0.w = lrelu(acc[3]) * fold[w * 8 + 3] + fold[32 + w * 8 + 3];
    o1.x = lrelu(acc[4]) * fold[w * 8 + 4] + fold[32 + w * 8 + 4];
    o1.y = lrelu(acc[5]) * fold[w * 8 + 5] + fold[32 + w * 8 + 5];
    o1.z = lrelu(acc[6]) * fold[w * 8 + 6] + fold[32 + w * 8 + 6];
    o1.w = lrelu(acc[7]) * fold[w * 8 + 7] + fold[32 + w * 8 + 7];
    *(float4*)(hS + lane * 36 + w * 8) = o0;
    *(float4*)(hS + lane * 36 + w * 8 + 4) = o1;
  }
  __syncthreads();

  {
    const float* W2p = W2 + w * 16;
    float o[16];
#pragma unroll
    for (int c = 0; c < 16; ++c) o[c] = b2[w * 16 + c];
    for (int k0 = 0; k0 < 32; k0 += 8) {
      float4 av0 = *(const float4*)(hS + lane * 36 + k0);
      float4 av1 = *(const float4*)(hS + lane * 36 + k0 + 4);
      float a[8] = {av0.x, av0.y, av0.z, av0.w, av1.x, av1.y, av1.z, av1.w};
#pragma unroll
      for (int j = 0; j < 8; ++j) {
#pragma unroll
        for (int c = 0; c < 16; ++c)
          o[c] = fmaf(a[j], W2p[(k0 + j) * 64 + c], o[c]);
      }
    }
    int gr = R + lane;
    if (gr < n) {
      float* op = out + (size_t)gr * 64 + w * 16;
#pragma unroll
      for (int c = 0; c < 16; ++c) op[c] = lrelu(o[c]);
    }
  }
}

// encoder blocks 1..4: in[64] -> h[32] (lrelu,BN) -> out[64] (lrelu)
__global__ __launch_bounds__(256) void k_encR_s(
    const float* __restrict__ xin,
    const float* __restrict__ W1, const float* __restrict__ b1,
    const float* __restrict__ fold,
    const float* __restrict__ W2, const float* __restrict__ b2,
    float* __restrict__ out, int n) {
  __shared__ float inS[64 * 68];
  __shared__ float hS[64 * 36];
  int t = threadIdx.x;
  int lane = t & 63;
  int w = __builtin_amdgcn_readfirstlane(t >> 6);
  int R = blockIdx.x * 64;

  for (int f = t; f < 1024; f += 256) {
    int row = f >> 4, c4 = (f & 15) << 2;
    int gr = R + row; if (gr >= n) gr = n - 1;
    *(float4*)(inS + row * 68 + c4) = *(const float4*)(xin + (size_t)gr * 64 + c4);
  }
  __syncthreads();

  {
    const float* W1p = W1 + w * 8;
    float acc[8];
#pragma unroll
    for (int c = 0; c < 8; ++c) acc[c] = b1[w * 8 + c];
    for (int k0 = 0; k0 < 64; k0 += 8) {
      float4 av0 = *(const float4*)(inS + lane * 68 + k0);
      float4 av1 = *(const float4*)(inS + lane * 68 + k0 + 4);
      float a[8] = {av0.x, av0.y, av0.z, av0.w, av1.x, av1.y, av1.z, av1.w};
#pragma unroll
      for (int j = 0; j < 8; ++j) {
#pragma unroll
        for (int c = 0; c < 8; ++c)
          acc[c] = fmaf(a[j], W1p[(k0 + j) * 32 + c], acc[c]);
      }
    }
    float4 o0, o1;
    o0.x = lrelu(acc[0]) * fold[w * 8 + 0] + fold[32 + w * 8 + 0];
    o0.y = lrelu(acc[1]) * fold[w * 8 + 1] + fold[32 + w * 8 + 1];
    o0.z = lrelu(acc[2]) * fold[w * 8 + 2] + fold[32 + w * 8 + 2];
    o0.w = lrelu(acc[3]) * fold[w * 8 + 3] + fold[32 + w * 8 + 3];
    o1.x = lrelu(acc[4]) * fold[w * 8 + 4] + fold[32 + w * 8 + 4];
    o1.y = lrelu(acc[5]) * fold[w * 8 + 5] + fold[32 + w * 8 + 5];
    o1.z = lrelu(acc[6]) * fold[w * 8 + 6] + fold[32 + w * 8 + 6];
    o1.w = lrelu(acc[7]) * fold[w * 8 + 7] + fold[32 + w * 8 + 7];
    *(float4*)(hS + lane * 36 + w * 8) = o0;
    *(float4*)(hS + lane * 36 + w * 8 + 4) = o1;
  }
  __syncthreads();

  {
    const float* W2p = W2 + w * 16;
    float o[16];
#pragma unroll
    for (int c = 0; c < 16; ++c) o[c] = b2[w * 16 + c];
    for (int k0 = 0; k0 < 32; k0 += 8) {
      float4 av0 = *(const float4*)(hS + lane * 36 + k0);
      float4 av1 = *(const float4*)(hS + lane * 36 + k0 + 4);
      float a[8] = {av0.x, av0.y, av0.z, av0.w, av1.x, av1.y, av1.z, av1.w};
#pragma unroll
      for (int j = 0; j < 8; ++j) {
#pragma unroll
        for (int c = 0; c < 16; ++c)
          o[c] = fmaf(a[j], W2p[(k0 + j) * 64 + c], o[c]);
      }
    }
    int gr = R + lane;
    if (gr < n) {
      float* op = out + (size_t)gr * 64 + w * 16;
#pragma unroll
      for (int c = 0; c < 16; ++c) op[c] = lrelu(o[c]);
    }
  }
}

// lastT = src @ decW[64:128] + decb. 512 thr, 8-col x 2-row, 128-row tile.
__global__ __launch_bounds__(512) void k_lastT(
    const float* __restrict__ src, const float* __restrict__ decW,
    const float* __restrict__ decb, float* __restrict__ lT, int n) {
  __shared__ float sS[128 * 68];
  int t = threadIdx.x;
  int lane = t & 63;
  int w = __builtin_amdgcn_readfirstlane(t >> 6);  // 0..7
  int R = blockIdx.x * 128;

  for (int f = t; f < 2048; f += 512) {
    int row = f >> 4, c4 = (f & 15) << 2;
    int gr = R + row; if (gr >= n) gr = n - 1;
    *(float4*)(sS + row * 68 + c4) = *(const float4*)(src + (size_t)gr * 64 + c4);
  }
  __syncthreads();

  const float* Dp = decW + 64 * 64 + w * 8;  // bottom half rows, 8-col slice
  float o0[8], o1[8];
#pragma unroll
  for (int c = 0; c < 8; ++c) { o0[c] = decb[w * 8 + c]; o1[c] = o0[c]; }
  for (int k0 = 0; k0 < 64; k0 += 8) {
    float4 av0 = *(const float4*)(sS + lane * 68 + k0);
    float4 av1 = *(const float4*)(sS + lane * 68 + k0 + 4);
    float4 bv0 = *(const float4*)(sS + (lane + 64) * 68 + k0);
    float4 bv1 = *(const float4*)(sS + (lane + 64) * 68 + k0 + 4);
    float a[8] = {av0.x, av0.y, av0.z, av0.w, av1.x, av1.y, av1.z, av1.w};
    float b[8] = {bv0.x, bv0.y, bv0.z, bv0.w, bv1.x, bv1.y, bv1.z, bv1.w};
#pragma unroll
    for (int j = 0; j < 8; ++j) {
#pragma unroll
      for (int c = 0; c < 8; ++c) {
        float wv = Dp[(k0 + j) * 64 + c];
        o0[c] = fmaf(a[j], wv, o0[c]);
        o1[c] = fmaf(b[j], wv, o1[c]);
      }
    }
  }
  int g0 = R + lane, g1 = R + 64 + lane;
  if (g0 < n) {
    float* op = lT + (size_t)g0 * 64 + w * 8;
#pragma unroll
    for (int c = 0; c < 8; ++c) op[c] = o0[c];
  }
  if (g1 < n) {
    float* op = lT + (size_t)g1 * 64 + w * 8;
#pragma unroll
    for (int c = 0; c < 8; ++c) op[c] = o1[c];
  }
}

// decoder: out = lrelu(BN(lrelu(cur@mlpW+mlpb) @ decW[0:64] + lastT[lrow]))
// In place. 512 thr (8 waves), 8-col x 2-row, 128-row tile, 34.8 KB LDS.
__global__ __launch_bounds__(512) void k_dec2(
    float* inout, const float* __restrict__ lT, const int* __restrict__ idx,
    const float* __restrict__ mlpW, const float* __restrict__ mlpb,
    const float* __restrict__ decW, const float* __restrict__ fold, int n) {
  __shared__ float curS[128 * 68];
  int t = threadIdx.x;
  int lane = t & 63;
  int w = __builtin_amdgcn_readfirstlane(t >> 6);  // 0..7
  int R = blockIdx.x * 128;

  for (int f = t; f < 2048; f += 512) {
    int row = f >> 4, c4 = (f & 15) << 2;
    int gr = R + row; if (gr >= n) gr = n - 1;
    *(float4*)(curS + row * 68 + c4) = *(const float4*)(inout + (size_t)gr * 64 + c4);
  }
  __syncthreads();

  // phase 1: skip cols 8w..8w+7 for rows lane, lane+64; K=64
  float s0[8], s1[8];
  {
    const float* Mp = mlpW + w * 8;
#pragma unroll
    for (int c = 0; c < 8; ++c) { s0[c] = mlpb[w * 8 + c]; s1[c] = s0[c]; }
    for (int k0 = 0; k0 < 64; k0 += 8) {
      float4 av0 = *(const float4*)(curS + lane * 68 + k0);
      float4 av1 = *(const float4*)(curS + lane * 68 + k0 + 4);
      float4 bv0 = *(const float4*)(curS + (lane + 64) * 68 + k0);
      float4 bv1 = *(const float4*)(curS + (lane + 64) * 68 + k0 + 4);
      float a[8] = {av0.x, av0.y, av0.z, av0.w, av1.x, av1.y, av1.z, av1.w};
      float b[8] = {bv0.x, bv0.y, bv0.z, bv0.w, bv1.x, bv1.y, bv1.z, bv1.w};
#pragma unroll
      for (int j = 0; j < 8; ++j) {
#pragma unroll
        for (int c = 0; c < 8; ++c) {
          float wv = Mp[(k0 + j) * 64 + c];
          s0[c] = fmaf(a[j], wv, s0[c]);
          s1[c] = fmaf(b[j], wv, s1[c]);
        }
      }
    }
  }
  __syncthreads();  // all reads of curS done
  {
    float4 t0 = {lrelu(s0[0]), lrelu(s0[1]), lrelu(s0[2]), lrelu(s0[3])};
    float4 t1 = {lrelu(s0[4]), lrelu(s0[5]), lrelu(s0[6]), lrelu(s0[7])};
    *(float4*)(curS + lane * 68 + w * 8 + 0) = t0;
    *(float4*)(curS + lane * 68 + w * 8 + 4) = t1;
    float4 u0 = {lrelu(s1[0]), lrelu(s1[1]), lrelu(s1[2]), lrelu(s1[3])};
    float4 u1 = {lrelu(s1[4]), lrelu(s1[5]), lrelu(s1[6]), lrelu(s1[7])};
    *(float4*)(curS + (lane + 64) * 68 + w * 8 + 0) = u0;
    *(float4*)(curS + (lane + 64) * 68 + w * 8 + 4) = u1;
  }
  __syncthreads();

  // phase 2: out = skip @ decW_top + lastT[lrow], K=64 (lT loaded here; TLP hides)
  {
    int g0r = R + lane; if (g0r >= n) g0r = n - 1;
    int g1r = R + 64 + lane; if (g1r >= n) g1r = n - 1;
    int g0i = idx ? idx[g0r] : g0r;
    int g1i = idx ? idx[g1r] : g1r;
    const float* lpa = lT + (size_t)g0i * 64 + w * 8;
    const float* lpb = lT + (size_t)g1i * 64 + w * 8;
    float4 la0 = *(const float4*)(lpa + 0);
    float4 la1 = *(const float4*)(lpa + 4);
    float4 lb0 = *(const float4*)(lpb + 0);
    float4 lb1 = *(const float4*)(lpb + 4);

    float o0[8], o1[8];
    o0[0] = la0.x; o0[1] = la0.y; o0[2] = la0.z; o0[3] = la0.w;
    o0[4] = la1.x; o0[5] = la1.y; o0[6] = la1.z; o0[7] = la1.w;
    o1[0] = lb0.x; o1[1] = lb0.y; o1[2] = lb0.z; o1[3] = lb0.w;
    o1[4] = lb1.x; o1[5] = lb1.y; o1[6] = lb1.z; o1[7] = lb1.w;

    const float* Dp = decW + w * 8;  // top half rows, 8-col slice
    for (int k0 = 0; k0 < 64; k0 += 8) {
      float4 av0 = *(const float4*)(curS + lane * 68 + k0);
      float4 av1 = *(const float4*)(curS + lane * 68 + k0 + 4);
      float4 bv0 = *(const float4*)(curS + (lane + 64) * 68 + k0);
      float4 bv1 = *(const float4*)(curS + (lane + 64) * 68 + k0 + 4);
      float a[8] = {av0.x, av0.y, av0.z, av0.w, av1.x, av1.y, av1.z, av1.w};
      float b[8] = {bv0.x, bv0.y, bv0.z, bv0.w, bv1.x, bv1.y, bv1.z, bv1.w};
#pragma unroll
      for (int j = 0; j < 8; ++j) {
#pragma unroll
        for (int c = 0; c < 8; ++c) {
          float wv = Dp[(k0 + j) * 64 + c];
          o0[c] = fmaf(a[j], wv, o0[c]);
          o1[c] = fmaf(b[j], wv, o1[c]);
        }
      }
    }
    int g0 = R + lane, g1 = R + 64 + lane;
    if (g0 < n) {
      float* op = inout + (size_t)g0 * 64 + w * 8;
#pragma unroll
      for (int c = 0; c < 8; ++c) {
        float sc = fold[w * 8 + c], sh = fold[64 + w * 8 + c];
        op[c] = lrelu(o0[c] * sc + sh);
      }
    }
    if (g1 < n) {
      float* op = inout + (size_t)g1 * 64 + w * 8;
#pragma unroll
      for (int c = 0; c < 8; ++c) {
        float sc = fold[w * 8 + c], sh = fold[64 + w * 8 + c];
        op[c] = lrelu(o1[c] * sc + sh);
      }
    }
  }
}

extern "C" void kernel_launch(void* const* d_in, const int* in_sizes, int n_in,
                              void* d_out, int out_size, void* d_ws, size_t ws_size,
                              hipStream_t stream) {
  const float* pt   = (const float*)d_in[0];
  const int* inv2   = (const int*)d_in[1];
  const int* inv4   = (const int*)d_in[2];
  const int* inv8   = (const int*)d_in[3];
  const int* inv16  = (const int*)d_in[4];
  const float* e0W1 = (const float*)d_in[5];
  const float* e0b1 = (const float*)d_in[6];
  const float* e0g  = (const float*)d_in[7];
  const float* e0be = (const float*)d_in[8];
  const float* e0m  = (const float*)d_in[9];
  const float* e0v  = (const float*)d_in[10];
  const float* e0W2 = (const float*)d_in[11];
  const float* e0b2 = (const float*)d_in[12];
  const float* eRW1 = (const float*)d_in[13];
  const float* eRb1 = (const float*)d_in[14];
  const float* eRg  = (const float*)d_in[15];
  const float* eRbe = (const float*)d_in[16];
  const float* eRm  = (const float*)d_in[17];
  const float* eRv  = (const float*)d_in[18];
  const float* eRW2 = (const float*)d_in[19];
  const float* eRb2 = (const float*)d_in[20];
  const float* mlpW = (const float*)d_in[21];
  const float* mlpb = (const float*)d_in[22];
  const float* decW = (const float*)d_in[23];
  const float* decb = (const float*)d_in[24];
  const float* decg = (const float*)d_in[25];
  const float* decbe= (const float*)d_in[26];
  const float* decm = (const float*)d_in[27];
  const float* decv = (const float*)d_in[28];

  float* s1 = (float*)d_out;
  float* s2 = s1 + (size_t)N1 * 64;
  float* s3 = s2 + (size_t)N2 * 64;
  float* s4 = s3 + (size_t)N4 * 64;
  float* s5 = s4 + (size_t)N8 * 64;

  // workspace: fold | oA (N2*64 f, reused as lastT) | oB (N4*64 f) | head | nxt
  float* fold = (float*)d_ws;
  float* oA   = fold + 1024;
  float* oB   = oA + (size_t)N2 * 64;
  int* head   = (int*)(oB + (size_t)N4 * 64);
  int* nxt    = head + N2;
  float* lT   = oA;  // free after encoders

  k_fold<<<1, 320, 0, stream>>>(e0g, e0be, e0m, e0v, eRg, eRbe, eRm, eRv,
                                decg, decbe, decm, decv, fold);

  // ---- level 1: enc0 on N1, pool -> oA [N2] ----
  hipMemsetAsync(head, 0xFF, (size_t)N2 * 4, stream);
  k_fill<<<(N1 + 255) / 256, 256, 0, stream>>>(inv2, head, nxt, N1);
  k_enc0_s<<<(N1 + 63) / 64, 256, 0, stream>>>(pt, e0W1, e0b1, fold, e0W2, e0b2, s1, N1);
  k_gmax<<<((size_t)N2 * 64 + 255) / 256, 256, 0, stream>>>(s1, head, nxt, oA, N2);

  // ---- level 2: encR[0] on N2, pool -> oB [N4] ----
  hipMemsetAsync(head, 0xFF, (size_t)N4 * 4, stream);
  k_fill<<<(N2 + 255) / 256, 256, 0, stream>>>(inv4, head, nxt, N2);
  k_encR_s<<<(N2 + 63) / 64, 256, 0, stream>>>(oA, eRW1 + 0 * 2048, eRb1 + 0 * 32,
                                               fold + 64 + 0 * 64, eRW2 + 0 * 2048,
                                               eRb2 + 0 * 64, s2, N2);
  k_gmax<<<((size_t)N4 * 64 + 255) / 256, 256, 0, stream>>>(s2, head, nxt, oB, N4);

  // ---- level 3: encR[1] on N4, pool -> oA [N8] ----
  hipMemsetAsync(head, 0xFF, (size_t)N8 * 4, stream);
  k_fill<<<(N4 + 255) / 256, 256, 0, stream>>>(inv8, head, nxt, N4);
  k_encR_s<<<(N4 + 63) / 64, 256, 0, stream>>>(oB, eRW1 + 1 * 2048, eRb1 + 1 * 32,
                                               fold + 64 + 1 * 64, eRW2 + 1 * 2048,
                                               eRb2 + 1 * 64, s3, N4);
  k_gmax<<<((size_t)N8 * 64 + 255) / 256, 256, 0, stream>>>(s3, head, nxt, oA, N8);

  // ---- level 4: encR[2] on N8, pool -> oB [N16] ----
  hipMemsetAsync(head, 0xFF, (size_t)N16 * 4, stream);
  k_fill<<<(N8 + 255) / 256, 256, 0, stream>>>(inv16, head, nxt, N8);
  k_encR_s<<<(N8 + 63) / 64, 256, 0, stream>>>(oA, eRW1 + 2 * 2048, eRb1 + 2 * 32,
                                               fold + 64 + 2 * 64, eRW2 + 2 * 2048,
                                               eRb2 + 2 * 64, s4, N8);
  k_gmax<<<((size_t)N16 * 64 + 255) / 256, 256, 0, stream>>>(s4, head, nxt, oB, N16);

  // ---- level 5: encR[3] on N16 ----
  k_encR_s<<<(N16 + 63) / 64, 256, 0, stream>>>(oB, eRW1 + 3 * 2048, eRb1 + 3 * 32,
                                                fold + 64 + 3 * 64, eRW2 + 3 * 2048,
                                                eRb2 + 3 * 64, s5, N16);

  // ---- decoders: lastT = prev_out @ decW_bot + decb, then fused dec ----
  k_lastT<<<(N16 + 127) / 128, 512, 0, stream>>>(s5, decW + 0 * 8192, decb + 0 * 64, lT, N16);
  k_dec2<<<(N16 + 127) / 128, 512, 0, stream>>>(s5, lT, nullptr, mlpW + 0 * 4096, mlpb + 0 * 64,
                                                decW + 0 * 8192, fold + 320 + 0 * 128, N16);
  k_lastT<<<(N16 + 127) / 128, 512, 0, stream>>>(s5, decW + 1 * 8192, decb + 1 * 64, lT, N16);
  k_dec2<<<(N8 + 127) / 128, 512, 0, stream>>>(s4, lT, inv16, mlpW + 1 * 4096, mlpb + 1 * 64,
                                               decW + 1 * 8192, fold + 320 + 1 * 128, N8);
  k_lastT<<<(N8 + 127) / 128, 512, 0, stream>>>(s4, decW + 2 * 8192, decb + 2 * 64, lT, N8);
  k_dec2<<<(N4 + 127) / 128, 512, 0, stream>>>(s3, lT, inv8, mlpW + 2 * 4096, mlpb + 2 * 64,
                                               decW + 2 * 8192, fold + 320 + 2 * 128, N4);
  k_lastT<<<(N4 + 127) / 128, 512, 0, stream>>>(s3, decW + 3 * 8192, decb + 3 * 64, lT, N4);
  k_dec2<<<(N2 + 127) / 128, 512, 0, stream>>>(s2, lT, inv4, mlpW + 3 * 4096, mlpb + 3 * 64,
                                               decW + 3 * 8192, fold + 320 + 3 * 128, N2);
  k_lastT<<<(N2 + 127) / 128, 512, 0, stream>>>(s2, decW + 4 * 8192, decb + 4 * 64, lT, N2);
  k_dec2<<<(N1 + 127) / 128, 512, 0, stream>>>(s1, lT, inv2, mlpW + 4 * 4096, mlpb + 4 * 64,
                                               decW + 4 * 8192, fold + 320 + 4 * 128, N1);
}